// Round 8
// baseline (773.805 us; speedup 1.0000x reference)
//
#include <hip/hip_runtime.h>
#include <hip/hip_cooperative_groups.h>

namespace cg = cooperative_groups;

#define N_NODES 50000
#define N_EDGES 800000
#define D 128
#define TN 16                 // nodes per block in the fused layer kernel
#define TSTR 136              // LDS row stride in bf16 elems (272B: 16B-aligned)
#define SCAN_BLOCKS 196       // ceil(50000/256)
#define COOP_BLOCKS 1024      // 4 blocks/CU -> guaranteed co-resident

typedef __attribute__((ext_vector_type(8))) short bf16x8;
typedef __attribute__((ext_vector_type(4))) float f32x4;

__device__ __forceinline__ unsigned short f32_to_bf16_rne(float f) {
    unsigned u = __float_as_uint(f);
    u += 0x7fffu + ((u >> 16) & 1u);
    return (unsigned short)(u >> 16);
}

__device__ __forceinline__ void acc_bf16x4(uint2 r, float& x, float& y, float& z, float& w) {
    x += __uint_as_float(r.x << 16);
    y += __uint_as_float(r.x & 0xffff0000u);
    z += __uint_as_float(r.y << 16);
    w += __uint_as_float(r.y & 0xffff0000u);
}

// U edge-pairs (2U edges) starting at i: lanes 0-31 even edge, 32-63 odd edge.
// U independent uint2 loads per thread in flight.
template <int U>
__device__ __forceinline__ void gather_phase(const unsigned short* __restrict__ hb,
                                             int myidx, int i, int sub, int q,
                                             float* ax, float* ay, float* az, float* aw) {
    int si[U];
    uint2 rr[U];
#pragma unroll
    for (int u = 0; u < U; ++u) si[u] = __shfl(myidx, i + 2 * u + sub, 64);
#pragma unroll
    for (int u = 0; u < U; ++u) rr[u] = *(const uint2*)(hb + (size_t)si[u] * D + 4 * q);
#pragma unroll
    for (int u = 0; u < U; ++u)
        acc_bf16x4(rr[u], ax[u & 3], ay[u & 3], az[u & 3], aw[u & 3]);
}

// ---------------------------------------------------------------------------
// One cooperative kernel for the whole CSR build + cvt + weight pack:
//  P0: zero counts
//  P1: histogram+rank (atomics), x fp32->bf16, weight fragment pack
//  P2: per-256-chunk sums of counts (blocks 0..195)
//  P3: exclusive scan of 196 chunk sums (block 0)
//  P4: per-chunk exclusive scan + chunk prefix -> offsets (blocks 0..195)
//  P5: atomic-free fill  esrc[offsets[dst]+rank] = src
// grid.sync() between phases (device-scope fence included).
// ---------------------------------------------------------------------------
__global__ __launch_bounds__(256) void csr_coop_kernel(
    const int* __restrict__ src, const int* __restrict__ dst,
    const float* __restrict__ x,
    const float* __restrict__ W1, const float* __restrict__ W2,
    const float* __restrict__ W3,
    int* __restrict__ counts, int* __restrict__ rank,
    int* __restrict__ offsets, int* __restrict__ bsum, int* __restrict__ bpre,
    int* __restrict__ esrc,
    unsigned short* __restrict__ Wb, unsigned short* __restrict__ xb) {

    cg::grid_group grid = cg::this_grid();
    __shared__ int s[256];

    const int tid = threadIdx.x;
    const int gtid = blockIdx.x * 256 + tid;
    const int GT = COOP_BLOCKS * 256;      // 262144

    // ---- P0: zero counts ----
    for (int i = gtid; i < N_NODES; i += GT) counts[i] = 0;
    grid.sync();

    // ---- P1: histogram + rank, x->bf16, wfrag ----
    for (int e = gtid; e < N_EDGES; e += GT)
        rank[e] = atomicAdd(&counts[dst[e]], 1);

    for (int t = gtid; t < N_NODES * D / 8; t += GT) {
        const float4 v0 = *(const float4*)(x + (size_t)t * 8);
        const float4 v1 = *(const float4*)(x + (size_t)t * 8 + 4);
        uint4 p;
        p.x = (unsigned)f32_to_bf16_rne(v0.x) | ((unsigned)f32_to_bf16_rne(v0.y) << 16);
        p.y = (unsigned)f32_to_bf16_rne(v0.z) | ((unsigned)f32_to_bf16_rne(v0.w) << 16);
        p.z = (unsigned)f32_to_bf16_rne(v1.x) | ((unsigned)f32_to_bf16_rne(v1.y) << 16);
        p.w = (unsigned)f32_to_bf16_rne(v1.z) | ((unsigned)f32_to_bf16_rne(v1.w) << 16);
        *(uint4*)(xb + (size_t)t * 8) = p;
    }

    // weight fragment pack: 3*128*128 = 49152 elems (single pass, gtid<49152)
    // B[k][n] for tile nt, chunk kc at Wb[((w*8+nt)*4+kc)*512 + lane*8 + j],
    // lane = quad*16+n, k = kc*32+quad*8+j, B[k][n] = W[nt*16+n][k].
    if (gtid < 3 * D * D) {
        const int w = gtid >> 14;          // /16384
        const int o = (gtid >> 7) & 127;
        const int k = gtid & 127;
        const float* W = (w == 0) ? W1 : (w == 1) ? W2 : W3;
        const unsigned short v = f32_to_bf16_rne(W[o * D + k]);
        const int nt = o >> 4, n = o & 15;
        const int kc = k >> 5, kr = k & 31, quad = kr >> 3, j = kr & 7;
        const int lane = quad * 16 + n;
        Wb[(((size_t)w * 8 + nt) * 4 + kc) * 512 + lane * 8 + j] = v;
    }
    grid.sync();

    // ---- P2: per-chunk sums (blocks 0..195) ----
    if (blockIdx.x < SCAN_BLOCKS) {
        const int i = blockIdx.x * 256 + tid;
        s[tid] = (i < N_NODES) ? counts[i] : 0;
        __syncthreads();
        for (int st = 128; st > 0; st >>= 1) {
            if (tid < st) s[tid] += s[tid + st];
            __syncthreads();
        }
        if (tid == 0) bsum[blockIdx.x] = s[0];
    }
    grid.sync();

    // ---- P3: scan of 196 chunk sums (block 0) ----
    if (blockIdx.x == 0) {
        const int v = (tid < SCAN_BLOCKS) ? bsum[tid] : 0;
        s[tid] = v;
        __syncthreads();
        for (int off = 1; off < 256; off <<= 1) {
            int a = (tid >= off) ? s[tid - off] : 0;
            __syncthreads();
            s[tid] += a;
            __syncthreads();
        }
        bpre[tid] = s[tid] - v;
        if (tid == 255) offsets[N_NODES] = s[255];
    }
    grid.sync();

    // ---- P4: offsets (blocks 0..195) ----
    if (blockIdx.x < SCAN_BLOCKS) {
        const int i = blockIdx.x * 256 + tid;
        const int v = (i < N_NODES) ? counts[i] : 0;
        s[tid] = v;
        __syncthreads();
        for (int off = 1; off < 256; off <<= 1) {
            int a = (tid >= off) ? s[tid - off] : 0;
            __syncthreads();
            s[tid] += a;
            __syncthreads();
        }
        const int excl = s[tid] - v + bpre[blockIdx.x];
        if (i < N_NODES) offsets[i] = excl;
    }
    grid.sync();

    // ---- P5: atomic-free fill ----
    for (int e = gtid; e < N_EDGES; e += GT)
        esrc[offsets[dst[e]] + rank[e]] = src[e];
}

// ---------------------------------------------------------------------------
// Fused layer: out[v] = (sum h[src_e] - deg[v]*h[v]) @ W^T + deg[v]*b
// Phase 1 gather: per node, one coalesced load pulls <=64 edge indices into
//   per-lane regs, shfl-broadcast. Main body: 16 edges/iter = 8 independent
//   uint2 row-loads in flight per thread, 4 acc sets; remainder phases 8/4/2/1.
//   Edge pairing across half-waves; shfl_xor(32) combine; t -> LDS bf16.
// Phase 2: 16x128x128 GEMM via 8 v_mfma_f32_16x16x32_bf16 per wave.
// ---------------------------------------------------------------------------
template <bool OUT_BF16>
__global__ __launch_bounds__(256) void gnn_layer_kernel(
    const unsigned short* __restrict__ hb,     // [N][D] bf16
    const int* __restrict__ offsets,
    const int* __restrict__ esrc,
    const unsigned short* __restrict__ Wb,     // fragment-ordered bf16 (this layer)
    const float* __restrict__ bias,
    float* __restrict__ outf,
    unsigned short* __restrict__ outb) {

    __shared__ __align__(16) unsigned short tb[TN][TSTR];
    __shared__ float degf[TN];

    const int tid = threadIdx.x;
    const int wave = tid >> 6;
    const int lane = tid & 63;
    const int sub = lane >> 5;        // edge parity within pair
    const int q = lane & 31;          // dim group: dims 4q..4q+3
    const int vbase = blockIdx.x * TN;

    // ---- phase 1: gather ----
    for (int j = wave * 4; j < wave * 4 + 4; ++j) {
        const int v = vbase + j;
        const int beg = offsets[v];
        const int deg = offsets[v + 1] - beg;

        float ax[4] = {0.f, 0.f, 0.f, 0.f};
        float ay[4] = {0.f, 0.f, 0.f, 0.f};
        float az[4] = {0.f, 0.f, 0.f, 0.f};
        float aw[4] = {0.f, 0.f, 0.f, 0.f};

        for (int base = 0; base < deg; base += 64) {
            const int cnt = min(deg - base, 64);
            int myidx = 0;
            if (lane < cnt) myidx = esrc[beg + base + lane];

            int i = 0;
            for (; i + 16 <= cnt; i += 16)
                gather_phase<8>(hb, myidx, i, sub, q, ax, ay, az, aw);
            if (i + 8 <= cnt) {
                gather_phase<4>(hb, myidx, i, sub, q, ax, ay, az, aw);
                i += 8;
            }
            if (i + 4 <= cnt) {
                gather_phase<2>(hb, myidx, i, sub, q, ax, ay, az, aw);
                i += 4;
            }
            if (i + 2 <= cnt) {
                gather_phase<1>(hb, myidx, i, sub, q, ax, ay, az, aw);
                i += 2;
            }
            if (i < cnt) {                       // odd tail: only sub==0 loads
                const int s0 = __shfl(myidx, i, 64);
                if (sub == 0) {
                    const uint2 r = *(const uint2*)(hb + (size_t)s0 * D + 4 * q);
                    acc_bf16x4(r, ax[0], ay[0], az[0], aw[0]);
                }
            }
        }

        float sx = (ax[0] + ax[1]) + (ax[2] + ax[3]);
        float sy = (ay[0] + ay[1]) + (ay[2] + ay[3]);
        float sz = (az[0] + az[1]) + (az[2] + az[3]);
        float sw = (aw[0] + aw[1]) + (aw[2] + aw[3]);

        sx += __shfl_xor(sx, 32, 64);
        sy += __shfl_xor(sy, 32, 64);
        sz += __shfl_xor(sz, 32, 64);
        sw += __shfl_xor(sw, 32, 64);

        const float dv = (float)deg;
        if (sub == 0) {
            const uint2 r = *(const uint2*)(hb + (size_t)v * D + 4 * q);
            const float tx = sx - dv * __uint_as_float(r.x << 16);
            const float ty = sy - dv * __uint_as_float(r.x & 0xffff0000u);
            const float tz = sz - dv * __uint_as_float(r.y << 16);
            const float tw = sw - dv * __uint_as_float(r.y & 0xffff0000u);
            unsigned p0 = (unsigned)f32_to_bf16_rne(tx) | ((unsigned)f32_to_bf16_rne(ty) << 16);
            unsigned p1 = (unsigned)f32_to_bf16_rne(tz) | ((unsigned)f32_to_bf16_rne(tw) << 16);
            *(uint2*)&tb[j][4 * q] = make_uint2(p0, p1);
        }
        if (lane == 0) degf[j] = dv;
    }
    __syncthreads();

    // ---- phase 2: MFMA GEMM  out[16][128] = t[16][128] @ Wt[128][128] ----
    const int n16 = lane & 15;
    const int quad = lane >> 4;

    bf16x8 afrag[4];
#pragma unroll
    for (int kc = 0; kc < 4; ++kc)
        afrag[kc] = *(const bf16x8*)&tb[n16][kc * 32 + quad * 8];

#pragma unroll
    for (int i = 0; i < 2; ++i) {
        const int nt = wave * 2 + i;
        f32x4 acc = {0.f, 0.f, 0.f, 0.f};
#pragma unroll
        for (int kc = 0; kc < 4; ++kc) {
            const bf16x8 bfrag = *(const bf16x8*)&Wb[((nt * 4 + kc) * 64 + lane) * 8];
            acc = __builtin_amdgcn_mfma_f32_16x16x32_bf16(afrag[kc], bfrag, acc, 0, 0, 0);
        }
        const int o = nt * 16 + n16;
        const float bo = bias[o];
#pragma unroll
        for (int r = 0; r < 4; ++r) {
            const int m = quad * 4 + r;
            const float val = acc[r] + degf[m] * bo;
            if (OUT_BF16)
                outb[(size_t)(vbase + m) * D + o] = f32_to_bf16_rne(val);
            else
                outf[(size_t)(vbase + m) * D + o] = val;
        }
    }
}

extern "C" void kernel_launch(void* const* d_in, const int* in_sizes, int n_in,
                              void* d_out, int out_size, void* d_ws, size_t ws_size,
                              hipStream_t stream) {
    const float* x  = (const float*)d_in[0];
    const float* W1 = (const float*)d_in[1];
    const float* b1 = (const float*)d_in[2];
    const float* W2 = (const float*)d_in[3];
    const float* b2 = (const float*)d_in[4];
    const float* W3 = (const float*)d_in[5];
    const float* b3 = (const float*)d_in[6];
    const int*   ei = (const int*)d_in[7];      // [2, E] int32
    // d_in[8] = edge_index_inter — unused by the reference

    const int* src = ei;            // row 0
    const int* dst = ei + N_EDGES;  // row 1
    float* out = (float*)d_out;

    // workspace layout (256B-aligned slabs)
    char* ws = (char*)d_ws;
    int* counts  = (int*)ws;                      ws += 204800;               // N ints
    int* offsets = (int*)ws;                      ws += 204800;               // N+1 ints
    int* bsum    = (int*)ws;                      ws += 1024;
    int* bpre    = (int*)ws;                      ws += 1024;
    int* rank    = (int*)ws;                      ws += (size_t)N_EDGES * 4;  // 3.2MB
    int* esrc    = (int*)ws;                      ws += (size_t)N_EDGES * 4;  // 3.2MB
    unsigned short* Wb = (unsigned short*)ws;     ws += 3 * 16384 * 2;        // 96KB
    unsigned short* xb = (unsigned short*)ws;     ws += (size_t)N_NODES * D * 2;
    unsigned short* h1 = (unsigned short*)ws;     ws += (size_t)N_NODES * D * 2;
    unsigned short* h2 = (unsigned short*)ws;

    // ---- CSR build + cvt + weight pack: single cooperative kernel ----
    {
        void* args[] = {
            (void*)&src, (void*)&dst, (void*)&x,
            (void*)&W1, (void*)&W2, (void*)&W3,
            (void*)&counts, (void*)&rank, (void*)&offsets,
            (void*)&bsum, (void*)&bpre, (void*)&esrc,
            (void*)&Wb, (void*)&xb
        };
        hipLaunchCooperativeKernel((const void*)csr_coop_kernel,
                                   dim3(COOP_BLOCKS), dim3(256), args, 0, stream);
    }

    const int blocks = N_NODES / TN;   // 3125

    gnn_layer_kernel<true ><<<blocks, 256, 0, stream>>>(xb, offsets, esrc, Wb,          b1, nullptr, h1);
    gnn_layer_kernel<true ><<<blocks, 256, 0, stream>>>(h1, offsets, esrc, Wb + 16384,  b2, nullptr, h2);
    gnn_layer_kernel<false><<<blocks, 256, 0, stream>>>(h2, offsets, esrc, Wb + 32768,  b3, out, nullptr);
}

// Round 9
// 298.574 us; speedup vs baseline: 2.5917x; 2.5917x over previous
//
#include <hip/hip_runtime.h>

#define N_NODES 50000
#define N_EDGES 800000
#define D 128
#define TN 16                 // nodes per block in the fused layer kernel
#define TSTR 136              // LDS row stride in bf16 elems (272B: 16B-aligned)
#define SCAN_BLOCKS 196       // ceil(50000/256)

typedef __attribute__((ext_vector_type(8))) short bf16x8;
typedef __attribute__((ext_vector_type(4))) float f32x4;

__device__ __forceinline__ unsigned short f32_to_bf16_rne(float f) {
    unsigned u = __float_as_uint(f);
    u += 0x7fffu + ((u >> 16) & 1u);
    return (unsigned short)(u >> 16);
}

__device__ __forceinline__ void acc_bf16x4(uint2 r, float& x, float& y, float& z, float& w) {
    x += __uint_as_float(r.x << 16);
    y += __uint_as_float(r.x & 0xffff0000u);
    z += __uint_as_float(r.y << 16);
    w += __uint_as_float(r.y & 0xffff0000u);
}

// U edge-pairs (2U edges) starting at i: lanes 0-31 even edge, 32-63 odd edge.
// U independent uint2 loads per thread in flight.
template <int U>
__device__ __forceinline__ void gather_phase(const unsigned short* __restrict__ hb,
                                             int myidx, int i, int sub, int q,
                                             float* ax, float* ay, float* az, float* aw) {
    int si[U];
    uint2 rr[U];
#pragma unroll
    for (int u = 0; u < U; ++u) si[u] = __shfl(myidx, i + 2 * u + sub, 64);
#pragma unroll
    for (int u = 0; u < U; ++u) rr[u] = *(const uint2*)(hb + (size_t)si[u] * D + 4 * q);
#pragma unroll
    for (int u = 0; u < U; ++u)
        acc_bf16x4(rr[u], ax[u & 3], ay[u & 3], az[u & 3], aw[u & 3]);
}

// ---------------------------------------------------------------------------
// prep: rank[e] = position of edge e within its dst bucket (ushort)
//       AND x fp32 -> bf16 (8 elems/thread; 800K threads covers both)
// ---------------------------------------------------------------------------
__global__ void prep_kernel(const int* __restrict__ dst, int* __restrict__ counts,
                            unsigned short* __restrict__ rank,
                            const float* __restrict__ x, unsigned short* __restrict__ xb) {
    const int t = blockIdx.x * blockDim.x + threadIdx.x;
    if (t < N_EDGES) {
        rank[t] = (unsigned short)atomicAdd(&counts[dst[t]], 1);
    }
    {
        const float4 v0 = *(const float4*)(x + (size_t)t * 8);
        const float4 v1 = *(const float4*)(x + (size_t)t * 8 + 4);
        uint4 p;
        p.x = (unsigned)f32_to_bf16_rne(v0.x) | ((unsigned)f32_to_bf16_rne(v0.y) << 16);
        p.y = (unsigned)f32_to_bf16_rne(v0.z) | ((unsigned)f32_to_bf16_rne(v0.w) << 16);
        p.z = (unsigned)f32_to_bf16_rne(v1.x) | ((unsigned)f32_to_bf16_rne(v1.y) << 16);
        p.w = (unsigned)f32_to_bf16_rne(v1.z) | ((unsigned)f32_to_bf16_rne(v1.w) << 16);
        *(uint4*)(xb + (size_t)t * 8) = p;
    }
}

// ---------------------------------------------------------------------------
// Scan A: per-block (256-wide) sums of counts -> bsum[196]
// ---------------------------------------------------------------------------
__global__ void block_sum_kernel(const int* __restrict__ counts, int* __restrict__ bsum) {
    __shared__ int red[256];
    const int tid = threadIdx.x;
    const int i = blockIdx.x * 256 + tid;
    red[tid] = (i < N_NODES) ? counts[i] : 0;
    __syncthreads();
    for (int s = 128; s > 0; s >>= 1) {
        if (tid < s) red[tid] += red[tid + s];
        __syncthreads();
    }
    if (tid == 0) bsum[blockIdx.x] = red[0];
}

// ---------------------------------------------------------------------------
// Scan B: exclusive scan of the 196 block sums (single tiny block)
// ---------------------------------------------------------------------------
__global__ void bsum_scan_kernel(const int* __restrict__ bsum,
                                 int* __restrict__ bpre,
                                 int* __restrict__ offsets) {
    __shared__ int s[256];
    const int tid = threadIdx.x;
    const int v = (tid < SCAN_BLOCKS) ? bsum[tid] : 0;
    s[tid] = v;
    __syncthreads();
    for (int off = 1; off < 256; off <<= 1) {
        int a = (tid >= off) ? s[tid - off] : 0;
        __syncthreads();
        s[tid] += a;
        __syncthreads();
    }
    bpre[tid] = s[tid] - v;
    if (tid == 255) offsets[N_NODES] = s[255];
}

// ---------------------------------------------------------------------------
// Scan C (blocks 0..195): per-block exclusive scan + block prefix -> offsets
// wfrag (blocks 196..387): pack all 3 weights as bf16 MFMA B-fragments.
//   B[k][n] for tile nt, chunk kc at Wb[((w*8+nt)*4+kc)*512 + lane*8 + j],
//   lane = quad*16+n, k = kc*32+quad*8+j, B[k][n] = W[nt*16+n][k].
// ---------------------------------------------------------------------------
__global__ void offsets_wfrag_kernel(const int* __restrict__ counts,
                                     const int* __restrict__ bpre,
                                     int* __restrict__ offsets,
                                     const float* __restrict__ W1,
                                     const float* __restrict__ W2,
                                     const float* __restrict__ W3,
                                     unsigned short* __restrict__ Wb) {
    if (blockIdx.x < SCAN_BLOCKS) {
        __shared__ int s[256];
        const int tid = threadIdx.x;
        const int i = blockIdx.x * 256 + tid;
        const int v = (i < N_NODES) ? counts[i] : 0;
        s[tid] = v;
        __syncthreads();
        for (int off = 1; off < 256; off <<= 1) {
            int a = (tid >= off) ? s[tid - off] : 0;
            __syncthreads();
            s[tid] += a;
            __syncthreads();
        }
        const int excl = s[tid] - v + bpre[blockIdx.x];
        if (i < N_NODES) offsets[i] = excl;
    } else {
        const int unit = (blockIdx.x - SCAN_BLOCKS) * 2 + (threadIdx.x >> 7); // 0..383
        const int w = unit >> 7;
        const int o = unit & 127;
        const int k = threadIdx.x & 127;
        const float* W = (w == 0) ? W1 : (w == 1) ? W2 : W3;
        const unsigned short v = f32_to_bf16_rne(W[o * D + k]);
        const int nt = o >> 4, n = o & 15;
        const int kc = k >> 5, kr = k & 31, quad = kr >> 3, j = kr & 7;
        const int lane = quad * 16 + n;
        Wb[(((size_t)w * 8 + nt) * 4 + kc) * 512 + lane * 8 + j] = v;
    }
}

// ---------------------------------------------------------------------------
// CSR fill, atomic-free: esrc[offsets[dst[e]] + rank[e]] = src[e]  (ushort)
// ---------------------------------------------------------------------------
__global__ void fill_kernel(const int* __restrict__ src, const int* __restrict__ dst,
                            const unsigned short* __restrict__ rank,
                            const int* __restrict__ offsets,
                            unsigned short* __restrict__ esrc) {
    int e = blockIdx.x * blockDim.x + threadIdx.x;
    if (e < N_EDGES) {
        esrc[offsets[dst[e]] + (int)rank[e]] = (unsigned short)src[e];
    }
}

// ---------------------------------------------------------------------------
// Fused layer: out[v] = (sum h[src_e] - deg[v]*h[v]) @ W^T + deg[v]*b
// Block = 1024 threads (16 waves), TN=16 nodes/block, ONE node per wave.
// Phase 1 gather: one coalesced ushort load pulls <=64 edge indices into
//   per-lane regs, shfl-broadcast. Main body: 16 edges/iter = 8 independent
//   uint2 row-loads in flight per thread, 4 acc sets; remainder 8/4/2/1.
//   Edge pairing across half-waves; shfl_xor(32) combine; t -> LDS bf16.
// Phase 2 (waves 0-3 only): 16x128x128 GEMM, 8 v_mfma_f32_16x16x32_bf16/wave.
// ---------------------------------------------------------------------------
template <bool OUT_BF16>
__global__ __launch_bounds__(1024) void gnn_layer_kernel(
    const unsigned short* __restrict__ hb,     // [N][D] bf16
    const int* __restrict__ offsets,
    const unsigned short* __restrict__ esrc,
    const unsigned short* __restrict__ Wb,     // fragment-ordered bf16 (this layer)
    const float* __restrict__ bias,
    float* __restrict__ outf,
    unsigned short* __restrict__ outb) {

    __shared__ __align__(16) unsigned short tb[TN][TSTR];
    __shared__ float degf[TN];

    const int tid = threadIdx.x;
    const int wave = tid >> 6;        // 0..15: one node per wave
    const int lane = tid & 63;
    const int sub = lane >> 5;        // edge parity within pair
    const int q = lane & 31;          // dim group: dims 4q..4q+3
    const int vbase = blockIdx.x * TN;

    // ---- phase 1: gather (node j == wave) ----
    {
        const int j = wave;
        const int v = vbase + j;
        const int beg = offsets[v];
        const int deg = offsets[v + 1] - beg;

        float ax[4] = {0.f, 0.f, 0.f, 0.f};
        float ay[4] = {0.f, 0.f, 0.f, 0.f};
        float az[4] = {0.f, 0.f, 0.f, 0.f};
        float aw[4] = {0.f, 0.f, 0.f, 0.f};

        for (int base = 0; base < deg; base += 64) {
            const int cnt = min(deg - base, 64);
            int myidx = 0;
            if (lane < cnt) myidx = (int)esrc[beg + base + lane];

            int i = 0;
            for (; i + 16 <= cnt; i += 16)
                gather_phase<8>(hb, myidx, i, sub, q, ax, ay, az, aw);
            if (i + 8 <= cnt) {
                gather_phase<4>(hb, myidx, i, sub, q, ax, ay, az, aw);
                i += 8;
            }
            if (i + 4 <= cnt) {
                gather_phase<2>(hb, myidx, i, sub, q, ax, ay, az, aw);
                i += 4;
            }
            if (i + 2 <= cnt) {
                gather_phase<1>(hb, myidx, i, sub, q, ax, ay, az, aw);
                i += 2;
            }
            if (i < cnt) {                       // odd tail: only sub==0 loads
                const int s0 = __shfl(myidx, i, 64);
                if (sub == 0) {
                    const uint2 r = *(const uint2*)(hb + (size_t)s0 * D + 4 * q);
                    acc_bf16x4(r, ax[0], ay[0], az[0], aw[0]);
                }
            }
        }

        float sx = (ax[0] + ax[1]) + (ax[2] + ax[3]);
        float sy = (ay[0] + ay[1]) + (ay[2] + ay[3]);
        float sz = (az[0] + az[1]) + (az[2] + az[3]);
        float sw = (aw[0] + aw[1]) + (aw[2] + aw[3]);

        sx += __shfl_xor(sx, 32, 64);
        sy += __shfl_xor(sy, 32, 64);
        sz += __shfl_xor(sz, 32, 64);
        sw += __shfl_xor(sw, 32, 64);

        const float dv = (float)deg;
        if (sub == 0) {
            const uint2 r = *(const uint2*)(hb + (size_t)v * D + 4 * q);
            const float tx = sx - dv * __uint_as_float(r.x << 16);
            const float ty = sy - dv * __uint_as_float(r.x & 0xffff0000u);
            const float tz = sz - dv * __uint_as_float(r.y << 16);
            const float tw = sw - dv * __uint_as_float(r.y & 0xffff0000u);
            unsigned p0 = (unsigned)f32_to_bf16_rne(tx) | ((unsigned)f32_to_bf16_rne(ty) << 16);
            unsigned p1 = (unsigned)f32_to_bf16_rne(tz) | ((unsigned)f32_to_bf16_rne(tw) << 16);
            *(uint2*)&tb[j][4 * q] = make_uint2(p0, p1);
        }
        if (lane == 0) degf[j] = dv;
    }
    __syncthreads();

    // ---- phase 2: MFMA GEMM (waves 0-3): out[16][128] = t @ Wt + deg⊗b ----
    if (wave < 4) {
        const int n16 = lane & 15;
        const int quad = lane >> 4;

        bf16x8 afrag[4];
#pragma unroll
        for (int kc = 0; kc < 4; ++kc)
            afrag[kc] = *(const bf16x8*)&tb[n16][kc * 32 + quad * 8];

#pragma unroll
        for (int i = 0; i < 2; ++i) {
            const int nt = wave * 2 + i;
            f32x4 acc = {0.f, 0.f, 0.f, 0.f};
#pragma unroll
            for (int kc = 0; kc < 4; ++kc) {
                const bf16x8 bfrag = *(const bf16x8*)&Wb[((nt * 4 + kc) * 64 + lane) * 8];
                acc = __builtin_amdgcn_mfma_f32_16x16x32_bf16(afrag[kc], bfrag, acc, 0, 0, 0);
            }
            const int o = nt * 16 + n16;
            const float bo = bias[o];
#pragma unroll
            for (int r = 0; r < 4; ++r) {
                const int m = quad * 4 + r;
                const float val = acc[r] + degf[m] * bo;
                if (OUT_BF16)
                    outb[(size_t)(vbase + m) * D + o] = f32_to_bf16_rne(val);
                else
                    outf[(size_t)(vbase + m) * D + o] = val;
            }
        }
    }
}

extern "C" void kernel_launch(void* const* d_in, const int* in_sizes, int n_in,
                              void* d_out, int out_size, void* d_ws, size_t ws_size,
                              hipStream_t stream) {
    const float* x  = (const float*)d_in[0];
    const float* W1 = (const float*)d_in[1];
    const float* b1 = (const float*)d_in[2];
    const float* W2 = (const float*)d_in[3];
    const float* b2 = (const float*)d_in[4];
    const float* W3 = (const float*)d_in[5];
    const float* b3 = (const float*)d_in[6];
    const int*   ei = (const int*)d_in[7];      // [2, E] int32
    // d_in[8] = edge_index_inter — unused by the reference

    const int* src = ei;            // row 0
    const int* dst = ei + N_EDGES;  // row 1
    float* out = (float*)d_out;

    // workspace layout (256B-aligned slabs)
    char* ws = (char*)d_ws;
    int* counts  = (int*)ws;                          ws += 204800;               // N ints
    int* offsets = (int*)ws;                          ws += 204800;               // N+1 ints
    int* bsum    = (int*)ws;                          ws += 1024;
    int* bpre    = (int*)ws;                          ws += 1024;
    unsigned short* rank = (unsigned short*)ws;       ws += (size_t)N_EDGES * 2;  // 1.6MB
    unsigned short* esrc = (unsigned short*)ws;       ws += (size_t)N_EDGES * 2;  // 1.6MB
    unsigned short* Wb = (unsigned short*)ws;         ws += 3 * 16384 * 2;        // 96KB
    unsigned short* xb = (unsigned short*)ws;         ws += (size_t)N_NODES * D * 2;
    unsigned short* h1 = (unsigned short*)ws;         ws += (size_t)N_NODES * D * 2;
    unsigned short* h2 = (unsigned short*)ws;

    // ---- CSR build + cvt + weight pack ----
    hipMemsetAsync(counts, 0, N_NODES * sizeof(int), stream);
    prep_kernel<<<(N_EDGES + 255) / 256, 256, 0, stream>>>(dst, counts, rank, x, xb);
    block_sum_kernel<<<SCAN_BLOCKS, 256, 0, stream>>>(counts, bsum);
    bsum_scan_kernel<<<1, 256, 0, stream>>>(bsum, bpre, offsets);
    offsets_wfrag_kernel<<<SCAN_BLOCKS + 192, 256, 0, stream>>>(counts, bpre, offsets,
                                                                W1, W2, W3, Wb);
    fill_kernel<<<(N_EDGES + 255) / 256, 256, 0, stream>>>(src, dst, rank, offsets, esrc);

    const int blocks = N_NODES / TN;   // 3125

    gnn_layer_kernel<true ><<<blocks, 1024, 0, stream>>>(xb, offsets, esrc, Wb,          b1, nullptr, h1);
    gnn_layer_kernel<true ><<<blocks, 1024, 0, stream>>>(h1, offsets, esrc, Wb + 16384,  b2, nullptr, h2);
    gnn_layer_kernel<false><<<blocks, 1024, 0, stream>>>(h2, offsets, esrc, Wb + 32768,  b3, out, nullptr);
}

// Round 10
// 263.922 us; speedup vs baseline: 2.9319x; 1.1313x over previous
//
#include <hip/hip_runtime.h>

#define N_NODES 50000
#define N_EDGES 800000
#define D 128
#define TN 16                 // nodes per block in the fused layer kernel
#define TSTR 136              // LDS row stride in bf16 elems (272B: 16B-aligned)
#define SCAN_BLOCKS 196       // ceil(50000/256)

typedef __attribute__((ext_vector_type(8))) short bf16x8;
typedef __attribute__((ext_vector_type(4))) float f32x4;

__device__ __forceinline__ unsigned short f32_to_bf16_rne(float f) {
    unsigned u = __float_as_uint(f);
    u += 0x7fffu + ((u >> 16) & 1u);
    return (unsigned short)(u >> 16);
}

__device__ __forceinline__ void acc_bf16x4(uint2 r, float& x, float& y, float& z, float& w) {
    x += __uint_as_float(r.x << 16);
    y += __uint_as_float(r.x & 0xffff0000u);
    z += __uint_as_float(r.y << 16);
    w += __uint_as_float(r.y & 0xffff0000u);
}

// U edge-pairs (2U edges) starting at i: lanes 0-31 even edge, 32-63 odd edge.
// U independent uint2 loads per thread in flight.
template <int U>
__device__ __forceinline__ void gather_phase(const unsigned short* __restrict__ hb,
                                             int myidx, int i, int sub, int q,
                                             float* ax, float* ay, float* az, float* aw) {
    int si[U];
    uint2 rr[U];
#pragma unroll
    for (int u = 0; u < U; ++u) si[u] = __shfl(myidx, i + 2 * u + sub, 64);
#pragma unroll
    for (int u = 0; u < U; ++u) rr[u] = *(const uint2*)(hb + (size_t)si[u] * D + 4 * q);
#pragma unroll
    for (int u = 0; u < U; ++u)
        acc_bf16x4(rr[u], ax[u & 3], ay[u & 3], az[u & 3], aw[u & 3]);
}

// ---------------------------------------------------------------------------
// prep: rank[e] = position of edge e within its dst bucket (ushort)
//       AND x fp32 -> bf16 (8 elems/thread; 800K threads covers both)
// ---------------------------------------------------------------------------
__global__ void prep_kernel(const int* __restrict__ dst, int* __restrict__ counts,
                            unsigned short* __restrict__ rank,
                            const float* __restrict__ x, unsigned short* __restrict__ xb) {
    const int t = blockIdx.x * blockDim.x + threadIdx.x;
    if (t < N_EDGES) {
        rank[t] = (unsigned short)atomicAdd(&counts[dst[t]], 1);
    }
    {
        const float4 v0 = *(const float4*)(x + (size_t)t * 8);
        const float4 v1 = *(const float4*)(x + (size_t)t * 8 + 4);
        uint4 p;
        p.x = (unsigned)f32_to_bf16_rne(v0.x) | ((unsigned)f32_to_bf16_rne(v0.y) << 16);
        p.y = (unsigned)f32_to_bf16_rne(v0.z) | ((unsigned)f32_to_bf16_rne(v0.w) << 16);
        p.z = (unsigned)f32_to_bf16_rne(v1.x) | ((unsigned)f32_to_bf16_rne(v1.y) << 16);
        p.w = (unsigned)f32_to_bf16_rne(v1.z) | ((unsigned)f32_to_bf16_rne(v1.w) << 16);
        *(uint4*)(xb + (size_t)t * 8) = p;
    }
}

// ---------------------------------------------------------------------------
// Scan A: per-block (256-wide) sums of counts -> bsum[196]
// ---------------------------------------------------------------------------
__global__ void block_sum_kernel(const int* __restrict__ counts, int* __restrict__ bsum) {
    __shared__ int red[256];
    const int tid = threadIdx.x;
    const int i = blockIdx.x * 256 + tid;
    red[tid] = (i < N_NODES) ? counts[i] : 0;
    __syncthreads();
    for (int s = 128; s > 0; s >>= 1) {
        if (tid < s) red[tid] += red[tid + s];
        __syncthreads();
    }
    if (tid == 0) bsum[blockIdx.x] = red[0];
}

// ---------------------------------------------------------------------------
// Scan B: exclusive scan of the 196 block sums (single tiny block)
// ---------------------------------------------------------------------------
__global__ void bsum_scan_kernel(const int* __restrict__ bsum,
                                 int* __restrict__ bpre,
                                 int* __restrict__ offsets) {
    __shared__ int s[256];
    const int tid = threadIdx.x;
    const int v = (tid < SCAN_BLOCKS) ? bsum[tid] : 0;
    s[tid] = v;
    __syncthreads();
    for (int off = 1; off < 256; off <<= 1) {
        int a = (tid >= off) ? s[tid - off] : 0;
        __syncthreads();
        s[tid] += a;
        __syncthreads();
    }
    bpre[tid] = s[tid] - v;
    if (tid == 255) offsets[N_NODES] = s[255];
}

// ---------------------------------------------------------------------------
// Scan C (blocks 0..195): per-block exclusive scan + block prefix -> offsets
// wfrag (blocks 196..387): pack all 3 weights as bf16 MFMA B-fragments.
//   B[k][n] for tile nt, chunk kc at Wb[((w*8+nt)*4+kc)*512 + lane*8 + j],
//   lane = quad*16+n, k = kc*32+quad*8+j, B[k][n] = W[nt*16+n][k].
// ---------------------------------------------------------------------------
__global__ void offsets_wfrag_kernel(const int* __restrict__ counts,
                                     const int* __restrict__ bpre,
                                     int* __restrict__ offsets,
                                     const float* __restrict__ W1,
                                     const float* __restrict__ W2,
                                     const float* __restrict__ W3,
                                     unsigned short* __restrict__ Wb) {
    if (blockIdx.x < SCAN_BLOCKS) {
        __shared__ int s[256];
        const int tid = threadIdx.x;
        const int i = blockIdx.x * 256 + tid;
        const int v = (i < N_NODES) ? counts[i] : 0;
        s[tid] = v;
        __syncthreads();
        for (int off = 1; off < 256; off <<= 1) {
            int a = (tid >= off) ? s[tid - off] : 0;
            __syncthreads();
            s[tid] += a;
            __syncthreads();
        }
        const int excl = s[tid] - v + bpre[blockIdx.x];
        if (i < N_NODES) offsets[i] = excl;
    } else {
        const int unit = (blockIdx.x - SCAN_BLOCKS) * 2 + (threadIdx.x >> 7); // 0..383
        const int w = unit >> 7;
        const int o = unit & 127;
        const int k = threadIdx.x & 127;
        const float* W = (w == 0) ? W1 : (w == 1) ? W2 : W3;
        const unsigned short v = f32_to_bf16_rne(W[o * D + k]);
        const int nt = o >> 4, n = o & 15;
        const int kc = k >> 5, kr = k & 31, quad = kr >> 3, j = kr & 7;
        const int lane = quad * 16 + n;
        Wb[(((size_t)w * 8 + nt) * 4 + kc) * 512 + lane * 8 + j] = v;
    }
}

// ---------------------------------------------------------------------------
// CSR fill, atomic-free: esrc[offsets[dst[e]] + rank[e]] = src[e]  (ushort)
// ---------------------------------------------------------------------------
__global__ void fill_kernel(const int* __restrict__ src, const int* __restrict__ dst,
                            const unsigned short* __restrict__ rank,
                            const int* __restrict__ offsets,
                            unsigned short* __restrict__ esrc) {
    int e = blockIdx.x * blockDim.x + threadIdx.x;
    if (e < N_EDGES) {
        esrc[offsets[dst[e]] + (int)rank[e]] = (unsigned short)src[e];
    }
}

// ---------------------------------------------------------------------------
// Fused layer: out[v] = (sum h[src_e] - deg[v]*h[v]) @ W^T + deg[v]*b
// Block = 256 threads (4 waves), TN=16 nodes/block, 4 serial nodes per wave
// (serial-over-nodes beats wave-parallel: sum-of-4 Poisson has lower rel.
//  variance than max-of-16 — R9 lesson).
// Phase 1 gather: one coalesced ushort load pulls <=64 edge indices into
//   per-lane regs, shfl-broadcast. Main body: 16 edges/iter = 8 independent
//   uint2 row-loads in flight per thread, 4 acc sets; remainder 8/4/2/1.
//   Edge pairing across half-waves; shfl_xor(32) combine; t -> LDS bf16.
// Phase 2: 16x128x128 GEMM via 8 v_mfma_f32_16x16x32_bf16 per wave.
// ---------------------------------------------------------------------------
template <bool OUT_BF16>
__global__ __launch_bounds__(256) void gnn_layer_kernel(
    const unsigned short* __restrict__ hb,     // [N][D] bf16
    const int* __restrict__ offsets,
    const unsigned short* __restrict__ esrc,
    const unsigned short* __restrict__ Wb,     // fragment-ordered bf16 (this layer)
    const float* __restrict__ bias,
    float* __restrict__ outf,
    unsigned short* __restrict__ outb) {

    __shared__ __align__(16) unsigned short tb[TN][TSTR];
    __shared__ float degf[TN];

    const int tid = threadIdx.x;
    const int wave = tid >> 6;
    const int lane = tid & 63;
    const int sub = lane >> 5;        // edge parity within pair
    const int q = lane & 31;          // dim group: dims 4q..4q+3
    const int vbase = blockIdx.x * TN;

    // ---- phase 1: gather ----
    for (int j = wave * 4; j < wave * 4 + 4; ++j) {
        const int v = vbase + j;
        const int beg = offsets[v];
        const int deg = offsets[v + 1] - beg;

        float ax[4] = {0.f, 0.f, 0.f, 0.f};
        float ay[4] = {0.f, 0.f, 0.f, 0.f};
        float az[4] = {0.f, 0.f, 0.f, 0.f};
        float aw[4] = {0.f, 0.f, 0.f, 0.f};

        for (int base = 0; base < deg; base += 64) {
            const int cnt = min(deg - base, 64);
            int myidx = 0;
            if (lane < cnt) myidx = (int)esrc[beg + base + lane];

            int i = 0;
            for (; i + 16 <= cnt; i += 16)
                gather_phase<8>(hb, myidx, i, sub, q, ax, ay, az, aw);
            if (i + 8 <= cnt) {
                gather_phase<4>(hb, myidx, i, sub, q, ax, ay, az, aw);
                i += 8;
            }
            if (i + 4 <= cnt) {
                gather_phase<2>(hb, myidx, i, sub, q, ax, ay, az, aw);
                i += 4;
            }
            if (i + 2 <= cnt) {
                gather_phase<1>(hb, myidx, i, sub, q, ax, ay, az, aw);
                i += 2;
            }
            if (i < cnt) {                       // odd tail: only sub==0 loads
                const int s0 = __shfl(myidx, i, 64);
                if (sub == 0) {
                    const uint2 r = *(const uint2*)(hb + (size_t)s0 * D + 4 * q);
                    acc_bf16x4(r, ax[0], ay[0], az[0], aw[0]);
                }
            }
        }

        float sx = (ax[0] + ax[1]) + (ax[2] + ax[3]);
        float sy = (ay[0] + ay[1]) + (ay[2] + ay[3]);
        float sz = (az[0] + az[1]) + (az[2] + az[3]);
        float sw = (aw[0] + aw[1]) + (aw[2] + aw[3]);

        sx += __shfl_xor(sx, 32, 64);
        sy += __shfl_xor(sy, 32, 64);
        sz += __shfl_xor(sz, 32, 64);
        sw += __shfl_xor(sw, 32, 64);

        const float dv = (float)deg;
        if (sub == 0) {
            const uint2 r = *(const uint2*)(hb + (size_t)v * D + 4 * q);
            const float tx = sx - dv * __uint_as_float(r.x << 16);
            const float ty = sy - dv * __uint_as_float(r.x & 0xffff0000u);
            const float tz = sz - dv * __uint_as_float(r.y << 16);
            const float tw = sw - dv * __uint_as_float(r.y & 0xffff0000u);
            unsigned p0 = (unsigned)f32_to_bf16_rne(tx) | ((unsigned)f32_to_bf16_rne(ty) << 16);
            unsigned p1 = (unsigned)f32_to_bf16_rne(tz) | ((unsigned)f32_to_bf16_rne(tw) << 16);
            *(uint2*)&tb[j][4 * q] = make_uint2(p0, p1);
        }
        if (lane == 0) degf[j] = dv;
    }
    __syncthreads();

    // ---- phase 2: MFMA GEMM  out[16][128] = t[16][128] @ Wt[128][128] ----
    const int n16 = lane & 15;
    const int quad = lane >> 4;

    bf16x8 afrag[4];
#pragma unroll
    for (int kc = 0; kc < 4; ++kc)
        afrag[kc] = *(const bf16x8*)&tb[n16][kc * 32 + quad * 8];

#pragma unroll
    for (int i = 0; i < 2; ++i) {
        const int nt = wave * 2 + i;
        f32x4 acc = {0.f, 0.f, 0.f, 0.f};
#pragma unroll
        for (int kc = 0; kc < 4; ++kc) {
            const bf16x8 bfrag = *(const bf16x8*)&Wb[((nt * 4 + kc) * 64 + lane) * 8];
            acc = __builtin_amdgcn_mfma_f32_16x16x32_bf16(afrag[kc], bfrag, acc, 0, 0, 0);
        }
        const int o = nt * 16 + n16;
        const float bo = bias[o];
#pragma unroll
        for (int r = 0; r < 4; ++r) {
            const int m = quad * 4 + r;
            const float val = acc[r] + degf[m] * bo;
            if (OUT_BF16)
                outb[(size_t)(vbase + m) * D + o] = f32_to_bf16_rne(val);
            else
                outf[(size_t)(vbase + m) * D + o] = val;
        }
    }
}

extern "C" void kernel_launch(void* const* d_in, const int* in_sizes, int n_in,
                              void* d_out, int out_size, void* d_ws, size_t ws_size,
                              hipStream_t stream) {
    const float* x  = (const float*)d_in[0];
    const float* W1 = (const float*)d_in[1];
    const float* b1 = (const float*)d_in[2];
    const float* W2 = (const float*)d_in[3];
    const float* b2 = (const float*)d_in[4];
    const float* W3 = (const float*)d_in[5];
    const float* b3 = (const float*)d_in[6];
    const int*   ei = (const int*)d_in[7];      // [2, E] int32
    // d_in[8] = edge_index_inter — unused by the reference

    const int* src = ei;            // row 0
    const int* dst = ei + N_EDGES;  // row 1
    float* out = (float*)d_out;

    // workspace layout (256B-aligned slabs)
    char* ws = (char*)d_ws;
    int* counts  = (int*)ws;                          ws += 204800;               // N ints
    int* offsets = (int*)ws;                          ws += 204800;               // N+1 ints
    int* bsum    = (int*)ws;                          ws += 1024;
    int* bpre    = (int*)ws;                          ws += 1024;
    unsigned short* rank = (unsigned short*)ws;       ws += (size_t)N_EDGES * 2;  // 1.6MB
    unsigned short* esrc = (unsigned short*)ws;       ws += (size_t)N_EDGES * 2;  // 1.6MB
    unsigned short* Wb = (unsigned short*)ws;         ws += 3 * 16384 * 2;        // 96KB
    unsigned short* xb = (unsigned short*)ws;         ws += (size_t)N_NODES * D * 2;
    unsigned short* h1 = (unsigned short*)ws;         ws += (size_t)N_NODES * D * 2;
    unsigned short* h2 = (unsigned short*)ws;

    // ---- CSR build + cvt + weight pack ----
    hipMemsetAsync(counts, 0, N_NODES * sizeof(int), stream);
    prep_kernel<<<(N_EDGES + 255) / 256, 256, 0, stream>>>(dst, counts, rank, x, xb);
    block_sum_kernel<<<SCAN_BLOCKS, 256, 0, stream>>>(counts, bsum);
    bsum_scan_kernel<<<1, 256, 0, stream>>>(bsum, bpre, offsets);
    offsets_wfrag_kernel<<<SCAN_BLOCKS + 192, 256, 0, stream>>>(counts, bpre, offsets,
                                                                W1, W2, W3, Wb);
    fill_kernel<<<(N_EDGES + 255) / 256, 256, 0, stream>>>(src, dst, rank, offsets, esrc);

    const int blocks = N_NODES / TN;   // 3125

    gnn_layer_kernel<true ><<<blocks, 256, 0, stream>>>(xb, offsets, esrc, Wb,          b1, nullptr, h1);
    gnn_layer_kernel<true ><<<blocks, 256, 0, stream>>>(h1, offsets, esrc, Wb + 16384,  b2, nullptr, h2);
    gnn_layer_kernel<false><<<blocks, 256, 0, stream>>>(h2, offsets, esrc, Wb + 32768,  b3, out, nullptr);
}